// Round 14
// baseline (316.368 us; speedup 1.0000x reference)
//
#include <hip/hip_runtime.h>
#include <hip/hip_bf16.h>
#include <math.h>

#define HEADS  8
#define TT     32
#define DMODEL 512
#define HWSZ   1024
#define TSTRIDE (HWSZ*DMODEL)

#define NQKV (3*DMODEL*DMODEL)   // 786432
#define NOUT (DMODEL*DMODEL)     // 262144
#define NTAB 512

typedef __attribute__((ext_vector_type(8)))  short bf16x8;
typedef __attribute__((ext_vector_type(16))) float f32x16;
typedef __attribute__((ext_vector_type(4)))  short s16x4;
typedef __attribute__((ext_vector_type(2)))  unsigned int u32x2;

__device__ __forceinline__ unsigned short f2bf(float f) {   // RNE f32->bf16
    unsigned int u = __builtin_bit_cast(unsigned int, f);
    u += 0x7FFFu + ((u >> 16) & 1u);
    return (unsigned short)(u >> 16);
}

__device__ __forceinline__ unsigned int pk_bf(float a, float b) {  // low=a, high=b
    return (unsigned int)f2bf(a) | ((unsigned int)f2bf(b) << 16);
}

__device__ __forceinline__ f32x16 fz16() {
    f32x16 v = {0.f,0.f,0.f,0.f,0.f,0.f,0.f,0.f,0.f,0.f,0.f,0.f,0.f,0.f,0.f,0.f};
    return v;
}

// ---------------- prep: weights -> bf16 MFMA16-fragment order + rope tables ----
__global__ __launch_bounds__(256)
void taa_prep(const float* __restrict__ wqkv, const float* __restrict__ wout,
              unsigned short* __restrict__ ws) {
    long i = (long)blockIdx.x * 256 + threadIdx.x;
    unsigned short* wqf = ws;
    unsigned short* wof = ws + NQKV;
    float* cs = (float*)(wof + NOUT);
    float* sn = cs + NTAB;
    if (i < NQKV) {
        int i8 = (int)(i & 7), lane = (int)((i >> 3) & 63), blk = (int)(i >> 9);
        int k05 = blk & 15, t = blk >> 4;
        int n = t * 16 + (lane & 15);
        int k = k05 * 32 + (lane >> 4) * 8 + i8;
        wqf[i] = f2bf(wqkv[(long)k * 1536 + n]);
    } else if (i < NQKV + NOUT) {
        long j = i - NQKV;
        int i8 = (int)(j & 7), lane = (int)((j >> 3) & 63), blk = (int)(j >> 9);
        int k05 = blk & 15, t = blk >> 4;
        int col = t * 16 + (lane & 15);
        int k = k05 * 32 + (lane >> 4) * 8 + i8;
        wof[j] = f2bf(wout[(long)k * 512 + col]);
    } else if (i < NQKV + NOUT + NTAB) {
        int j = (int)(i - NQKV - NOUT);
        int t = j >> 4, f = j & 15;
        float inv = powf(10000.f, -(float)(2 * f) / 32.f);
        float sv, cv;
        sincosf((float)t * inv, &sv, &cv);
        cs[j] = cv; sn[j] = sv;
    }
}

// ---------------- LDS layout (bytes) — identical to round 13 ------------------
#define X_OFF  0
#define Q_OFF  65536
#define K_OFF  81920
#define V_OFF  98304
#define PV_OFF 114688
#define CS_OFF 131072
#define SN_OFF 133120
#define LDS_SZ 135168

#define XS(g, r, cB) (X_OFF + ((g) << 15) + ((r) << 10) + ((cB) ^ (((r) & 7) << 4)))
#define RS(base, r, cB) ((base) + ((r) << 7) + ((cB) ^ (((r) & 7) << 4)))
#define VS(base, d, cB) ((base) + ((d) << 6) + ((cB) ^ (((d) & 7) << 3)))

#define MFMA16(a, b, c) __builtin_amdgcn_mfma_f32_16x16x32_bf16((a), (b), (c), 0, 0, 0)
#define MFMA32(a, b, c) __builtin_amdgcn_mfma_f32_32x32x16_bf16((a), (b), (c), 0, 0, 0)

__global__ __launch_bounds__(512, 1)
void taa_main(const float* __restrict__ x,
              const unsigned short* __restrict__ ws,
              const float* __restrict__ b_out,
              float* __restrict__ out) {
    extern __shared__ __align__(16) unsigned char smem[];

    const unsigned short* wqf = ws;
    const unsigned short* wof = ws + NQKV;
    const float* cs_gl = (const float*)(wof + NOUT);
    const float* sn_gl = cs_gl + NTAB;

    const int tid  = threadIdx.x;
    const int lane = tid & 63;
    const int wv   = tid >> 6;                 // wave 0..7
    const int quad = lane >> 4;
    const int lid  = lane & 15;

    const int n0 = blockIdx.x * 2;
    const long long base0 = ((long long)(n0 >> 10) * (TT * HWSZ) + (n0 & 1023)) * DMODEL;
    const int n1 = n0 + 1;
    const long long base1 = ((long long)(n1 >> 10) * (TT * HWSZ) + (n1 & 1023)) * DMODEL;

    float* cs_l = (float*)(smem + CS_OFF);
    float* sn_l = (float*)(smem + SN_OFF);
    for (int i = tid; i < NTAB; i += 512) { cs_l[i] = cs_gl[i]; sn_l[i] = sn_gl[i]; }

    // ---- stage x (both groups): fp32 global -> bf16 swizzled LDS ----
    for (int idx = tid; idx < 4096; idx += 512) {
        int g  = idx >> 11;
        int r  = (idx >> 6) & 31;
        int c8 = idx & 63;
        long long bg = g ? base1 : base0;
        const float4* src = (const float4*)(x + bg + (long long)r * TSTRIDE + c8 * 8);
        float4 f0 = src[0], f1 = src[1];
        s16x4 lo, hi;
        lo[0] = (short)f2bf(f0.x); lo[1] = (short)f2bf(f0.y);
        lo[2] = (short)f2bf(f0.z); lo[3] = (short)f2bf(f0.w);
        hi[0] = (short)f2bf(f1.x); hi[1] = (short)f2bf(f1.y);
        hi[2] = (short)f2bf(f1.z); hi[3] = (short)f2bf(f1.w);
        int a = XS(g, r, c8 * 16);
        *(s16x4*)(smem + a)     = lo;
        *(s16x4*)(smem + a + 8) = hi;
    }

    typedef __attribute__((ext_vector_type(4))) float f32x4;
    f32x4 oacc[4][2][2];                       // [col-tile j][group][row-tile]
    #pragma unroll
    for (int j = 0; j < 4; ++j)
        #pragma unroll
        for (int g = 0; g < 2; ++g)
            #pragma unroll
            for (int mt = 0; mt < 2; ++mt) oacc[j][g][mt] = (f32x4){0.f, 0.f, 0.f, 0.f};

    __syncthreads();

    // qkv-phase wave role: head-in-pair qhh, 16-col tile qt16 (8 roles = 8 waves)
    const int qhh  = wv >> 2;
    const int qt16 = wv & 3;

    for (int it = 0; it < 4; ++it) {           // 2 heads per iteration
        const int hpair = it * 2;

        // ===== qkv GEMM, 3-chain: one A-stream feeds q,k,v per K-step ==========
        // A-reads: 2 (mt) per k05 instead of 4 tiles x re-stream (3x LDS cut).
        // g-loop OUTER so live acc = 24 VGPR (epilogue per g frees them).
        {
            const int hd = hpair + qhh;
            const unsigned short* wpq = wqf + ((long)((     hd * 4 + qt16) * 16)) * 512 + lane * 8;
            const unsigned short* wpk = wqf + ((long)((32 + hd * 4 + qt16) * 16)) * 512 + lane * 8;
            const unsigned short* wpv = wqf + ((long)((64 + hd * 4 + qt16) * 16)) * 512 + lane * 8;
            #pragma unroll
            for (int g = 0; g < 2; ++g) {
                f32x4 acc[3][2];               // [m: q,k,v][mt]
                #pragma unroll
                for (int m = 0; m < 3; ++m)
                    #pragma unroll
                    for (int mt = 0; mt < 2; ++mt) acc[m][mt] = (f32x4){0.f, 0.f, 0.f, 0.f};
                #pragma unroll 4
                for (int k05 = 0; k05 < 16; ++k05) {
                    bf16x8 a0 = *(const bf16x8*)(smem + XS(g, lid,      k05 * 64 + quad * 16));
                    bf16x8 a1 = *(const bf16x8*)(smem + XS(g, lid + 16, k05 * 64 + quad * 16));
                    bf16x8 bq = *(const bf16x8*)(wpq + (long)k05 * 512);
                    bf16x8 bk = *(const bf16x8*)(wpk + (long)k05 * 512);
                    bf16x8 bv = *(const bf16x8*)(wpv + (long)k05 * 512);
                    acc[0][0] = MFMA16(a0, bq, acc[0][0]);
                    acc[0][1] = MFMA16(a1, bq, acc[0][1]);
                    acc[1][0] = MFMA16(a0, bk, acc[1][0]);
                    acc[1][1] = MFMA16(a1, bk, acc[1][1]);
                    acc[2][0] = MFMA16(a0, bv, acc[2][0]);
                    acc[2][1] = MFMA16(a1, bv, acc[2][1]);
                }
                // ---- epilogues for this g (r13-verbatim patterns) ----
                // q, k: row-major [t][64] with RoPE on cols 0..31
                #pragma unroll
                for (int m = 0; m < 2; ++m) {
                    int dstb = ((m == 0) ? Q_OFF : K_OFF) + qhh * 4096 + g * 8192;
                    if (qt16 < 2) {            // rotary cols 0..31
                        #pragma unroll
                        for (int mt = 0; mt < 2; ++mt)
                            #pragma unroll
                            for (int r = 0; r < 4; ++r) {
                                float v = acc[m][mt][r];
                                float p = __shfl_xor(v, 1, 64);
                                int trow = mt * 16 + quad * 4 + r;
                                int colh = qt16 * 16 + lid;
                                int jj = colh >> 1;
                                float cv = cs_l[trow * 16 + jj];
                                float sv = sn_l[trow * 16 + jj];
                                float res = (colh & 1) ? (v * cv + p * sv) : (v * cv - p * sv);
                                *(unsigned short*)(smem + RS(dstb, trow, colh * 2)) = f2bf(res);
                            }
                    } else {
                        #pragma unroll
                        for (int mt = 0; mt < 2; ++mt)
                            #pragma unroll
                            for (int r = 0; r < 4; ++r) {
                                int trow = mt * 16 + quad * 4 + r;
                                *(unsigned short*)(smem + RS(dstb, trow, (qt16 * 16 + lid) * 2)) = f2bf(acc[m][mt][r]);
                            }
                    }
                }
                // v -> V^T [64 d][32 t]
                #pragma unroll
                for (int mt = 0; mt < 2; ++mt) {
                    int d  = qt16 * 16 + lid;
                    int t0 = mt * 16 + quad * 4;
                    s16x4 pk;
                    pk[0] = (short)f2bf(acc[2][mt][0]); pk[1] = (short)f2bf(acc[2][mt][1]);
                    pk[2] = (short)f2bf(acc[2][mt][2]); pk[3] = (short)f2bf(acc[2][mt][3]);
                    *(s16x4*)(smem + VS(V_OFF + (g * 2 + qhh) * 4096, d, t0 * 2)) = pk;
                }
            }
        }
        __syncthreads();

        // ===== attention: r13 verbatim (swapped PV + packed store) ==============
        {
            int g  = wv >> 2;
            int hh = (wv >> 1) & 1;
            int dt = wv & 1;
            int qr  = Q_OFF  + (g * 2 + hh) * 4096;
            int kr  = K_OFF  + (g * 2 + hh) * 4096;
            int vr  = V_OFF  + (g * 2 + hh) * 4096;
            int pvr = PV_OFF + (g * 2 + hh) * 4096;
            int tq = lane & 31;
            int hf = lane >> 5;

            f32x16 sc = fz16();
            #pragma unroll
            for (int j = 0; j < 4; ++j) {
                bf16x8 aK = *(const bf16x8*)(smem + RS(kr, tq, j * 32 + hf * 16));
                bf16x8 bQ = *(const bf16x8*)(smem + RS(qr, tq, j * 32 + hf * 16));
                sc = MFMA32(aK, bQ, sc);
            }
            float pe[16];
            float mx = -1e30f;
            #pragma unroll
            for (int r = 0; r < 16; ++r) {
                int tk = (r & 3) + 8 * (r >> 2) + 4 * hf;
                float v = (tk <= tq) ? sc[r] * 0.125f : -1e30f;
                pe[r] = v;
                mx = fmaxf(mx, v);
            }
            mx = fmaxf(mx, __shfl_xor(mx, 32, 64));
            float sum = 0.f;
            #pragma unroll
            for (int r = 0; r < 16; ++r) {
                float e = __expf(pe[r] - mx);
                pe[r] = e;
                sum += e;
            }
            sum += __shfl_xor(sum, 32, 64);
            float inv = 1.f / sum;
            bf16x8 pa0, pa1;
            #pragma unroll
            for (int i2 = 0; i2 < 8; ++i2) {
                pa0[i2] = (short)f2bf(pe[i2] * inv);
                pa1[i2] = (short)f2bf(pe[8 + i2] * inv);
            }
            int d = dt * 32 + tq;
            f32x16 o = fz16();
            {
                s16x4 lo = *(const s16x4*)(smem + VS(vr, d, 8 * hf));
                s16x4 hi = *(const s16x4*)(smem + VS(vr, d, 16 + 8 * hf));
                bf16x8 bv;
                bv[0] = lo[0]; bv[1] = lo[1]; bv[2] = lo[2]; bv[3] = lo[3];
                bv[4] = hi[0]; bv[5] = hi[1]; bv[6] = hi[2]; bv[7] = hi[3];
                o = MFMA32(bv, pa0, o);
            }
            {
                s16x4 lo = *(const s16x4*)(smem + VS(vr, d, 32 + 8 * hf));
                s16x4 hi = *(const s16x4*)(smem + VS(vr, d, 48 + 8 * hf));
                bf16x8 bv;
                bv[0] = lo[0]; bv[1] = lo[1]; bv[2] = lo[2]; bv[3] = lo[3];
                bv[4] = hi[0]; bv[5] = hi[1]; bv[6] = hi[2]; bv[7] = hi[3];
                o = MFMA32(bv, pa1, o);
            }
            #pragma unroll
            for (int c = 0; c < 4; ++c) {
                u32x2 pk2;
                pk2[0] = pk_bf(o[4 * c + 0], o[4 * c + 1]);
                pk2[1] = pk_bf(o[4 * c + 2], o[4 * c + 3]);
                int db = dt * 32 + c * 8 + 4 * hf;
                *(u32x2*)(smem + RS(pvr, tq, db * 2)) = pk2;
            }
        }
        __syncthreads();

        // ===== out-projection accumulate — r13 verbatim =========================
        {
            #pragma unroll
            for (int k05h = 0; k05h < 4; ++k05h) {
                int hh   = k05h >> 1;
                int dblk = k05h & 1;
                int kb   = (hpair + hh) * 2 + dblk;
                bf16x8 a[2][2];
                #pragma unroll
                for (int g = 0; g < 2; ++g)
                    #pragma unroll
                    for (int mt = 0; mt < 2; ++mt)
                        a[g][mt] = *(const bf16x8*)(smem + RS(PV_OFF + (g * 2 + hh) * 4096, lid + 16 * mt, dblk * 64 + quad * 16));
                #pragma unroll
                for (int j = 0; j < 4; ++j) {
                    int ct = wv + 8 * j;
                    bf16x8 bw = *(const bf16x8*)(wof + ((long)(ct * 16 + kb)) * 512 + lane * 8);
                    #pragma unroll
                    for (int g = 0; g < 2; ++g)
                        #pragma unroll
                        for (int mt = 0; mt < 2; ++mt)
                            oacc[j][g][mt] = MFMA16(a[g][mt], bw, oacc[j][g][mt]);
                }
            }
        }
        // no barrier: next-iter qkv writes Q/K/V (readers synced at attn barrier);
        // next-iter attn writes PV only after next qkv barrier.
    }

    // ===== write out (+bias) — r13 verbatim =====
    #pragma unroll
    for (int j = 0; j < 4; ++j) {
        int col = (wv + 8 * j) * 16 + lid;
        float bias = b_out[col];
        #pragma unroll
        for (int g = 0; g < 2; ++g) {
            long long bg = g ? base1 : base0;
            #pragma unroll
            for (int mt = 0; mt < 2; ++mt)
                #pragma unroll
                for (int r = 0; r < 4; ++r) {
                    int t = mt * 16 + quad * 4 + r;
                    out[bg + (long long)t * TSTRIDE + col] = oacc[j][g][mt][r] + bias;
                }
        }
    }
}

extern "C" void kernel_launch(void* const* d_in, const int* in_sizes, int n_in,
                              void* d_out, int out_size, void* d_ws, size_t ws_size,
                              hipStream_t stream) {
    const float* x     = (const float*)d_in[0];
    const float* w_qkv = (const float*)d_in[1];
    const float* w_out = (const float*)d_in[2];
    const float* b_out = (const float*)d_in[3];
    float* out = (float*)d_out;
    (void)in_sizes; (void)n_in; (void)out_size; (void)ws_size;

    unsigned short* ws = (unsigned short*)d_ws;   // ~2.1 MB

    taa_prep<<<dim3(4098), dim3(256), 0, stream>>>(w_qkv, w_out, ws);
    taa_main<<<dim3(1024), dim3(512), LDS_SZ, stream>>>(x, ws, b_out, out);
}

// Round 16
// 259.853 us; speedup vs baseline: 1.2175x; 1.2175x over previous
//
#include <hip/hip_runtime.h>
#include <hip/hip_bf16.h>
#include <math.h>

#define HEADS  8
#define TT     32
#define DMODEL 512
#define HWSZ   1024
#define TSTRIDE (HWSZ*DMODEL)

#define NQKV (3*DMODEL*DMODEL)   // 786432
#define NOUT (DMODEL*DMODEL)     // 262144
#define NTAB 512

typedef __attribute__((ext_vector_type(8)))  short bf16x8;
typedef __attribute__((ext_vector_type(16))) float f32x16;
typedef __attribute__((ext_vector_type(4)))  short s16x4;
typedef __attribute__((ext_vector_type(2)))  unsigned int u32x2;
typedef __attribute__((ext_vector_type(4)))  unsigned int u32x4;

__device__ __forceinline__ unsigned short f2bf(float f) {   // RNE f32->bf16
    unsigned int u = __builtin_bit_cast(unsigned int, f);
    u += 0x7FFFu + ((u >> 16) & 1u);
    return (unsigned short)(u >> 16);
}

// packed pair (low16=a, high16=b), pure C (bit-exact RNE; r12/r13-proven)
__device__ __forceinline__ unsigned int pk_bf(float a, float b) {
    return (unsigned int)f2bf(a) | ((unsigned int)f2bf(b) << 16);
}

__device__ __forceinline__ f32x16 fz16() {
    f32x16 v = {0.f,0.f,0.f,0.f,0.f,0.f,0.f,0.f,0.f,0.f,0.f,0.f,0.f,0.f,0.f,0.f};
    return v;
}

// ---------------- prep: weights -> bf16 MFMA16-fragment order + rope tables ----
// (verbatim from passing r13)
__global__ __launch_bounds__(256)
void taa_prep(const float* __restrict__ wqkv, const float* __restrict__ wout,
              unsigned short* __restrict__ ws) {
    long i = (long)blockIdx.x * 256 + threadIdx.x;
    unsigned short* wqf = ws;
    unsigned short* wof = ws + NQKV;
    float* cs = (float*)(wof + NOUT);
    float* sn = cs + NTAB;
    if (i < NQKV) {
        int i8 = (int)(i & 7), lane = (int)((i >> 3) & 63), blk = (int)(i >> 9);
        int k05 = blk & 15, t = blk >> 4;
        int n = t * 16 + (lane & 15);
        int k = k05 * 32 + (lane >> 4) * 8 + i8;
        wqf[i] = f2bf(wqkv[(long)k * 1536 + n]);
    } else if (i < NQKV + NOUT) {
        long j = i - NQKV;
        int i8 = (int)(j & 7), lane = (int)((j >> 3) & 63), blk = (int)(j >> 9);
        int k05 = blk & 15, t = blk >> 4;
        int col = t * 16 + (lane & 15);
        int k = k05 * 32 + (lane >> 4) * 8 + i8;
        wof[j] = f2bf(wout[(long)k * 512 + col]);
    } else if (i < NQKV + NOUT + NTAB) {
        int j = (int)(i - NQKV - NOUT);
        int t = j >> 4, f = j & 15;
        float inv = powf(10000.f, -(float)(2 * f) / 32.f);
        float sv, cv;
        sincosf((float)t * inv, &sv, &cv);
        cs[j] = cv; sn[j] = sv;
    }
}

// ---------------- LDS layout (bytes) — identical to round 13 ------------------
#define X_OFF  0
#define Q_OFF  65536
#define K_OFF  81920
#define V_OFF  98304
#define PV_OFF 114688
#define CS_OFF 131072
#define SN_OFF 133120
#define LDS_SZ 135168

#define XS(g, r, cB) (X_OFF + ((g) << 15) + ((r) << 10) + ((cB) ^ (((r) & 7) << 4)))
#define RS(base, r, cB) ((base) + ((r) << 7) + ((cB) ^ (((r) & 7) << 4)))
#define VS(base, d, cB) ((base) + ((d) << 6) + ((cB) ^ (((d) & 7) << 3)))

#define MFMA16(a, b, c) __builtin_amdgcn_mfma_f32_16x16x32_bf16((a), (b), (c), 0, 0, 0)
#define MFMA32(a, b, c) __builtin_amdgcn_mfma_f32_32x32x16_bf16((a), (b), (c), 0, 0, 0)

__global__ __launch_bounds__(512, 1)
void taa_main(const float* __restrict__ x,
              const unsigned short* __restrict__ ws,
              const float* __restrict__ b_out,
              float* __restrict__ out) {
    extern __shared__ __align__(16) unsigned char smem[];

    const unsigned short* wqf = ws;
    const unsigned short* wof = ws + NQKV;
    const float* cs_gl = (const float*)(wof + NOUT);
    const float* sn_gl = cs_gl + NTAB;

    const int tid  = threadIdx.x;
    const int lane = tid & 63;
    const int wv   = tid >> 6;                 // wave 0..7
    const int quad = lane >> 4;
    const int lid  = lane & 15;

    const int n0 = blockIdx.x * 2;
    const long long base0 = ((long long)(n0 >> 10) * (TT * HWSZ) + (n0 & 1023)) * DMODEL;
    const int n1 = n0 + 1;
    const long long base1 = ((long long)(n1 >> 10) * (TT * HWSZ) + (n1 & 1023)) * DMODEL;

    float* cs_l = (float*)(smem + CS_OFF);
    float* sn_l = (float*)(smem + SN_OFF);
    for (int i = tid; i < NTAB; i += 512) { cs_l[i] = cs_gl[i]; sn_l[i] = sn_gl[i]; }

    // ---- stage x (both groups): fp32 global -> bf16 swizzled LDS (packed) ----
    for (int idx = tid; idx < 4096; idx += 512) {
        int g  = idx >> 11;
        int r  = (idx >> 6) & 31;
        int c8 = idx & 63;
        long long bg = g ? base1 : base0;
        const float4* src = (const float4*)(x + bg + (long long)r * TSTRIDE + c8 * 8);
        float4 f0 = src[0], f1 = src[1];
        u32x2 A, B;
        A[0] = pk_bf(f0.x, f0.y); A[1] = pk_bf(f0.z, f0.w);
        B[0] = pk_bf(f1.x, f1.y); B[1] = pk_bf(f1.z, f1.w);
        int a = XS(g, r, c8 * 16);
        *(u32x2*)(smem + a)     = A;
        *(u32x2*)(smem + a + 8) = B;
    }

    typedef __attribute__((ext_vector_type(4))) float f32x4;
    f32x4 oacc[4][2][2];                       // [col-tile j][group][row-tile]
    #pragma unroll
    for (int j = 0; j < 4; ++j)
        #pragma unroll
        for (int g = 0; g < 2; ++g)
            #pragma unroll
            for (int mt = 0; mt < 2; ++mt) oacc[j][g][mt] = (f32x4){0.f, 0.f, 0.f, 0.f};

    __syncthreads();

    for (int it = 0; it < 4; ++it) {           // 2 heads per iteration
        const int hpair = it * 2;

        // ===== qkv GEMM: 24 col-tiles (2 heads), 3 balanced rounds — r13 loop ====
        for (int rnd = 0; rnd < 3; ++rnd) {
            int ct  = rnd * 8 + wv;            // 0..23
            int m   = ct >> 3;                 // 0=q 1=k 2=v
            int hh  = (ct >> 2) & 1;
            int t16 = ct & 3;
            int T   = m * 32 + (hpair + hh) * 4 + t16;
            const unsigned short* wp = wqf + ((long)T * 16) * 512 + lane * 8;
            f32x4 acc[2][2];
            #pragma unroll
            for (int g = 0; g < 2; ++g)
                #pragma unroll
                for (int mt = 0; mt < 2; ++mt) acc[g][mt] = (f32x4){0.f, 0.f, 0.f, 0.f};
            #pragma unroll 4
            for (int k05 = 0; k05 < 16; ++k05) {
                bf16x8 bw = *(const bf16x8*)(wp + (long)k05 * 512);
                #pragma unroll
                for (int g = 0; g < 2; ++g)
                    #pragma unroll
                    for (int mt = 0; mt < 2; ++mt) {
                        bf16x8 a = *(const bf16x8*)(smem + XS(g, lid + 16 * mt, k05 * 64 + quad * 16));
                        acc[g][mt] = MFMA16(a, bw, acc[g][mt]);
                    }
            }
            if (m < 2) {                       // q,k: row-major [t][64] with RoPE
                // PAIRED 4B STORES: even lane (lid&1==0, col=2j) holds x0=own,
                // x1=shfl partner -> computes BOTH rotated elems, one aligned
                // 4B store. Halves store count, kills same-dword conflicts.
                int dstb = ((m == 0) ? Q_OFF : K_OFF) + hh * 4096;
                if (t16 < 2) {                 // rotary cols 0..31
                    #pragma unroll
                    for (int g = 0; g < 2; ++g)
                        #pragma unroll
                        for (int mt = 0; mt < 2; ++mt)
                            #pragma unroll
                            for (int r = 0; r < 4; ++r) {
                                float v = acc[g][mt][r];
                                float p = __shfl_xor(v, 1, 64);   // all lanes
                                if ((lid & 1) == 0) {
                                    int trow = mt * 16 + quad * 4 + r;
                                    int colh = t16 * 16 + lid;    // even
                                    int jj = colh >> 1;
                                    float cv = cs_l[trow * 16 + jj];
                                    float sv = sn_l[trow * 16 + jj];
                                    float r0 = v * cv - p * sv;   // x0' = x0 c - x1 s
                                    float r1 = p * cv + v * sv;   // x1' = x1 c + x0 s
                                    *(unsigned int*)(smem + RS(dstb + g * 8192, trow, colh * 2)) = pk_bf(r0, r1);
                                }
                            }
                } else {
                    #pragma unroll
                    for (int g = 0; g < 2; ++g)
                        #pragma unroll
                        for (int mt = 0; mt < 2; ++mt)
                            #pragma unroll
                            for (int r = 0; r < 4; ++r) {
                                float v = acc[g][mt][r];
                                float p = __shfl_xor(v, 1, 64);   // all lanes
                                if ((lid & 1) == 0) {
                                    int trow = mt * 16 + quad * 4 + r;
                                    int colh = t16 * 16 + lid;
                                    *(unsigned int*)(smem + RS(dstb + g * 8192, trow, colh * 2)) = pk_bf(v, p);
                                }
                            }
                }
            } else {                           // v -> V^T [64 d][32 t], packed
                #pragma unroll
                for (int g = 0; g < 2; ++g)
                    #pragma unroll
                    for (int mt = 0; mt < 2; ++mt) {
                        int d  = t16 * 16 + lid;
                        int t0 = mt * 16 + quad * 4;
                        u32x2 pv2;
                        pv2[0] = pk_bf(acc[g][mt][0], acc[g][mt][1]);
                        pv2[1] = pk_bf(acc[g][mt][2], acc[g][mt][3]);
                        *(u32x2*)(smem + VS(V_OFF + (g * 2 + hh) * 4096, d, t0 * 2)) = pv2;
                    }
            }
        }
        __syncthreads();

        // ===== attention: r13 verbatim (swapped PV + packed store) ==============
        {
            int g  = wv >> 2;
            int hh = (wv >> 1) & 1;
            int dt = wv & 1;
            int qr  = Q_OFF  + (g * 2 + hh) * 4096;
            int kr  = K_OFF  + (g * 2 + hh) * 4096;
            int vr  = V_OFF  + (g * 2 + hh) * 4096;
            int pvr = PV_OFF + (g * 2 + hh) * 4096;
            int tq = lane & 31;
            int hf = lane >> 5;

            f32x16 sc = fz16();
            #pragma unroll
            for (int j = 0; j < 4; ++j) {
                bf16x8 aK = *(const bf16x8*)(smem + RS(kr, tq, j * 32 + hf * 16));
                bf16x8 bQ = *(const bf16x8*)(smem + RS(qr, tq, j * 32 + hf * 16));
                sc = MFMA32(aK, bQ, sc);
            }
            float pe[16];
            float mx = -1e30f;
            #pragma unroll
            for (int r = 0; r < 16; ++r) {
                int tk = (r & 3) + 8 * (r >> 2) + 4 * hf;
                float v = (tk <= tq) ? sc[r] * 0.125f : -1e30f;
                pe[r] = v;
                mx = fmaxf(mx, v);
            }
            mx = fmaxf(mx, __shfl_xor(mx, 32, 64));
            float sum = 0.f;
            #pragma unroll
            for (int r = 0; r < 16; ++r) {
                float e = __expf(pe[r] - mx);
                pe[r] = e;
                sum += e;
            }
            sum += __shfl_xor(sum, 32, 64);
            float inv = 1.f / sum;
            u32x4 P0, P1;
            #pragma unroll
            for (int i2 = 0; i2 < 4; ++i2) {
                P0[i2] = pk_bf(pe[2 * i2] * inv,     pe[2 * i2 + 1] * inv);
                P1[i2] = pk_bf(pe[8 + 2 * i2] * inv, pe[9 + 2 * i2] * inv);
            }
            bf16x8 pa0 = __builtin_bit_cast(bf16x8, P0);
            bf16x8 pa1 = __builtin_bit_cast(bf16x8, P1);
            // PV, swapped operands (verified r13): lane owns row tq, 4-consec-d runs
            int d = dt * 32 + tq;
            f32x16 o = fz16();
            {
                s16x4 lo = *(const s16x4*)(smem + VS(vr, d, 8 * hf));
                s16x4 hi = *(const s16x4*)(smem + VS(vr, d, 16 + 8 * hf));
                bf16x8 bv;
                bv[0] = lo[0]; bv[1] = lo[1]; bv[2] = lo[2]; bv[3] = lo[3];
                bv[4] = hi[0]; bv[5] = hi[1]; bv[6] = hi[2]; bv[7] = hi[3];
                o = MFMA32(bv, pa0, o);
            }
            {
                s16x4 lo = *(const s16x4*)(smem + VS(vr, d, 32 + 8 * hf));
                s16x4 hi = *(const s16x4*)(smem + VS(vr, d, 48 + 8 * hf));
                bf16x8 bv;
                bv[0] = lo[0]; bv[1] = lo[1]; bv[2] = lo[2]; bv[3] = lo[3];
                bv[4] = hi[0]; bv[5] = hi[1]; bv[6] = hi[2]; bv[7] = hi[3];
                o = MFMA32(bv, pa1, o);
            }
            #pragma unroll
            for (int c = 0; c < 4; ++c) {
                u32x2 pk2;
                pk2[0] = pk_bf(o[4 * c + 0], o[4 * c + 1]);
                pk2[1] = pk_bf(o[4 * c + 2], o[4 * c + 3]);
                int db = dt * 32 + c * 8 + 4 * hf;
                *(u32x2*)(smem + RS(pvr, tq, db * 2)) = pk2;
            }
        }
        __syncthreads();

        // ===== out-projection accumulate — r13 verbatim =========================
        {
            #pragma unroll
            for (int k05h = 0; k05h < 4; ++k05h) {
                int hh   = k05h >> 1;
                int dblk = k05h & 1;
                int kb   = (hpair + hh) * 2 + dblk;
                bf16x8 a[2][2];
                #pragma unroll
                for (int g = 0; g < 2; ++g)
                    #pragma unroll
                    for (int mt = 0; mt < 2; ++mt)
                        a[g][mt] = *(const bf16x8*)(smem + RS(PV_OFF + (g * 2 + hh) * 4096, lid + 16 * mt, dblk * 64 + quad * 16));
                #pragma unroll
                for (int j = 0; j < 4; ++j) {
                    int ct = wv + 8 * j;
                    bf16x8 bw = *(const bf16x8*)(wof + ((long)(ct * 16 + kb)) * 512 + lane * 8);
                    #pragma unroll
                    for (int g = 0; g < 2; ++g)
                        #pragma unroll
                        for (int mt = 0; mt < 2; ++mt)
                            oacc[j][g][mt] = MFMA16(a[g][mt], bw, oacc[j][g][mt]);
                }
            }
        }
        // no barrier: next-iter qkv writes Q/K/V (readers synced at attn barrier);
        // next-iter attn writes PV only after next qkv barrier.
    }

    // ===== write out (+bias) — r13 verbatim =====
    #pragma unroll
    for (int j = 0; j < 4; ++j) {
        int col = (wv + 8 * j) * 16 + lid;
        float bias = b_out[col];
        #pragma unroll
        for (int g = 0; g < 2; ++g) {
            long long bg = g ? base1 : base0;
            #pragma unroll
            for (int mt = 0; mt < 2; ++mt)
                #pragma unroll
                for (int r = 0; r < 4; ++r) {
                    int t = mt * 16 + quad * 4 + r;
                    out[bg + (long long)t * TSTRIDE + col] = oacc[j][g][mt][r] + bias;
                }
        }
    }
}

extern "C" void kernel_launch(void* const* d_in, const int* in_sizes, int n_in,
                              void* d_out, int out_size, void* d_ws, size_t ws_size,
                              hipStream_t stream) {
    const float* x     = (const float*)d_in[0];
    const float* w_qkv = (const float*)d_in[1];
    const float* w_out = (const float*)d_in[2];
    const float* b_out = (const float*)d_in[3];
    float* out = (float*)d_out;
    (void)in_sizes; (void)n_in; (void)out_size; (void)ws_size;

    unsigned short* ws = (unsigned short*)d_ws;   // ~2.1 MB

    taa_prep<<<dim3(4098), dim3(256), 0, stream>>>(w_qkv, w_out, ws);
    taa_main<<<dim3(1024), dim3(512), LDS_SZ, stream>>>(x, ws, b_out, out);
}

// Round 17
// 226.756 us; speedup vs baseline: 1.3952x; 1.1460x over previous
//
#include <hip/hip_runtime.h>
#include <hip/hip_bf16.h>
#include <math.h>

#define HEADS  8
#define TT     32
#define DMODEL 512
#define HWSZ   1024
#define TSTRIDE (HWSZ*DMODEL)

#define NQKV (3*DMODEL*DMODEL)   // 786432
#define NOUT (DMODEL*DMODEL)     // 262144
#define NTAB 512

typedef __attribute__((ext_vector_type(8)))  short bf16x8;
typedef __attribute__((ext_vector_type(16))) float f32x16;
typedef __attribute__((ext_vector_type(4)))  short s16x4;
typedef __attribute__((ext_vector_type(2)))  unsigned int u32x2;

__device__ __forceinline__ unsigned short f2bf(float f) {   // RNE f32->bf16
    unsigned int u = __builtin_bit_cast(unsigned int, f);
    u += 0x7FFFu + ((u >> 16) & 1u);
    return (unsigned short)(u >> 16);
}

__device__ __forceinline__ unsigned int pk_bf(float a, float b) {  // low=a, high=b
    return (unsigned int)f2bf(a) | ((unsigned int)f2bf(b) << 16);
}

__device__ __forceinline__ f32x16 fz16() {
    f32x16 v = {0.f,0.f,0.f,0.f,0.f,0.f,0.f,0.f,0.f,0.f,0.f,0.f,0.f,0.f,0.f,0.f};
    return v;
}

// ---------------- prep: weights -> bf16 MFMA16-fragment order + rope tables ----
// (verbatim from passing r13)
__global__ __launch_bounds__(256)
void taa_prep(const float* __restrict__ wqkv, const float* __restrict__ wout,
              unsigned short* __restrict__ ws) {
    long i = (long)blockIdx.x * 256 + threadIdx.x;
    unsigned short* wqf = ws;
    unsigned short* wof = ws + NQKV;
    float* cs = (float*)(wof + NOUT);
    float* sn = cs + NTAB;
    if (i < NQKV) {
        int i8 = (int)(i & 7), lane = (int)((i >> 3) & 63), blk = (int)(i >> 9);
        int k05 = blk & 15, t = blk >> 4;
        int n = t * 16 + (lane & 15);
        int k = k05 * 32 + (lane >> 4) * 8 + i8;
        wqf[i] = f2bf(wqkv[(long)k * 1536 + n]);
    } else if (i < NQKV + NOUT) {
        long j = i - NQKV;
        int i8 = (int)(j & 7), lane = (int)((j >> 3) & 63), blk = (int)(j >> 9);
        int k05 = blk & 15, t = blk >> 4;
        int col = t * 16 + (lane & 15);
        int k = k05 * 32 + (lane >> 4) * 8 + i8;
        wof[j] = f2bf(wout[(long)k * 512 + col]);
    } else if (i < NQKV + NOUT + NTAB) {
        int j = (int)(i - NQKV - NOUT);
        int t = j >> 4, f = j & 15;
        float inv = powf(10000.f, -(float)(2 * f) / 32.f);
        float sv, cv;
        sincosf((float)t * inv, &sv, &cv);
        cs[j] = cv; sn[j] = sv;
    }
}

// ---------------- LDS layout (bytes) ------------------------------------------
// X now FRAGMENT-LINEAR: per group g, 32 blocks (blk = mt*16 + k05) of 1KB;
// lane reads its A-frag at blk*1024 + ((lane*16) ^ ((blk&7)<<4)) — a wave read
// is an XOR-const bijection onto contiguous 1KB = conflict-free (m97 pattern).
#define X_OFF  0
#define Q_OFF  65536
#define K_OFF  81920
#define V_OFF  98304
#define PV_OFF 114688
#define CS_OFF 131072
#define SN_OFF 133120
#define LDS_SZ 135168

#define XF(g, blk, ln) (X_OFF + ((g) << 15) + ((blk) << 10) + ((((ln) << 4)) ^ (((blk) & 7) << 4)))
#define RS(base, r, cB) ((base) + ((r) << 7) + ((cB) ^ (((r) & 7) << 4)))
#define VS(base, d, cB) ((base) + ((d) << 6) + ((cB) ^ (((d) & 7) << 3)))

#define MFMA16(a, b, c) __builtin_amdgcn_mfma_f32_16x16x32_bf16((a), (b), (c), 0, 0, 0)
#define MFMA32(a, b, c) __builtin_amdgcn_mfma_f32_32x32x16_bf16((a), (b), (c), 0, 0, 0)

__global__ __launch_bounds__(512, 1)
void taa_main(const float* __restrict__ x,
              const unsigned short* __restrict__ ws,
              const float* __restrict__ b_out,
              float* __restrict__ out) {
    extern __shared__ __align__(16) unsigned char smem[];

    const unsigned short* wqf = ws;
    const unsigned short* wof = ws + NQKV;
    const float* cs_gl = (const float*)(wof + NOUT);
    const float* sn_gl = cs_gl + NTAB;

    const int tid  = threadIdx.x;
    const int lane = tid & 63;
    const int wv   = tid >> 6;                 // wave 0..7
    const int quad = lane >> 4;
    const int lid  = lane & 15;

    const int n0 = blockIdx.x * 2;
    const long long base0 = ((long long)(n0 >> 10) * (TT * HWSZ) + (n0 & 1023)) * DMODEL;
    const int n1 = n0 + 1;
    const long long base1 = ((long long)(n1 >> 10) * (TT * HWSZ) + (n1 & 1023)) * DMODEL;

    float* cs_l = (float*)(smem + CS_OFF);
    float* sn_l = (float*)(smem + SN_OFF);
    for (int i = tid; i < NTAB; i += 512) { cs_l[i] = cs_gl[i]; sn_l[i] = sn_gl[i]; }

    // ---- stage x (both groups): coalesced global read -> frag-order LDS write --
    // src chunk (r, c8) = elems X[r][c8*8 .. +7]  maps to  blk = (r>>4)*16 + (c8>>2),
    // frag-lane ln = (c8&3)<<4 | (r&15).  Write ~8-way spread via the blk&7 XOR.
    for (int idx = tid; idx < 4096; idx += 512) {
        int g  = idx >> 11;
        int r  = (idx >> 6) & 31;
        int c8 = idx & 63;
        long long bg = g ? base1 : base0;
        const float4* src = (const float4*)(x + bg + (long long)r * TSTRIDE + c8 * 8);
        float4 f0 = src[0], f1 = src[1];
        s16x4 lo, hi;
        lo[0] = (short)f2bf(f0.x); lo[1] = (short)f2bf(f0.y);
        lo[2] = (short)f2bf(f0.z); lo[3] = (short)f2bf(f0.w);
        hi[0] = (short)f2bf(f1.x); hi[1] = (short)f2bf(f1.y);
        hi[2] = (short)f2bf(f1.z); hi[3] = (short)f2bf(f1.w);
        int blk = ((r >> 4) << 4) + (c8 >> 2);
        int ln  = ((c8 & 3) << 4) | (r & 15);
        int dest = XF(g, blk, ln);
        *(s16x4*)(smem + dest)     = lo;
        *(s16x4*)(smem + dest + 8) = hi;
    }

    typedef __attribute__((ext_vector_type(4))) float f32x4;
    f32x4 oacc[4][2][2];                       // [col-tile j][group][row-tile]
    #pragma unroll
    for (int j = 0; j < 4; ++j)
        #pragma unroll
        for (int g = 0; g < 2; ++g)
            #pragma unroll
            for (int mt = 0; mt < 2; ++mt) oacc[j][g][mt] = (f32x4){0.f, 0.f, 0.f, 0.f};

    __syncthreads();

    for (int it = 0; it < 4; ++it) {           // 2 heads per iteration
        const int hpair = it * 2;

        // ===== qkv GEMM: 24 col-tiles (2 heads), 3 balanced rounds — r13 loop ====
        for (int rnd = 0; rnd < 3; ++rnd) {
            int ct  = rnd * 8 + wv;            // 0..23
            int m   = ct >> 3;                 // 0=q 1=k 2=v
            int hh  = (ct >> 2) & 1;
            int t16 = ct & 3;
            int T   = m * 32 + (hpair + hh) * 4 + t16;
            const unsigned short* wp = wqf + ((long)T * 16) * 512 + lane * 8;
            f32x4 acc[2][2];
            #pragma unroll
            for (int g = 0; g < 2; ++g)
                #pragma unroll
                for (int mt = 0; mt < 2; ++mt) acc[g][mt] = (f32x4){0.f, 0.f, 0.f, 0.f};
            #pragma unroll 4
            for (int k05 = 0; k05 < 16; ++k05) {
                bf16x8 bw = *(const bf16x8*)(wp + (long)k05 * 512);
                #pragma unroll
                for (int g = 0; g < 2; ++g)
                    #pragma unroll
                    for (int mt = 0; mt < 2; ++mt) {
                        bf16x8 a = *(const bf16x8*)(smem + XF(g, mt * 16 + k05, lane));
                        acc[g][mt] = MFMA16(a, bw, acc[g][mt]);
                    }
            }
            if (m < 2) {                       // q,k: row-major [t][64] with RoPE
                int dstb = ((m == 0) ? Q_OFF : K_OFF) + hh * 4096;
                if (t16 < 2) {                 // rotary cols 0..31
                    #pragma unroll
                    for (int g = 0; g < 2; ++g)
                        #pragma unroll
                        for (int mt = 0; mt < 2; ++mt)
                            #pragma unroll
                            for (int r = 0; r < 4; ++r) {
                                float v = acc[g][mt][r];
                                float p = __shfl_xor(v, 1, 64);
                                int trow = mt * 16 + quad * 4 + r;
                                int colh = t16 * 16 + lid;
                                int jj = colh >> 1;
                                float cv = cs_l[trow * 16 + jj];
                                float sv = sn_l[trow * 16 + jj];
                                float res = (colh & 1) ? (v * cv + p * sv) : (v * cv - p * sv);
                                *(unsigned short*)(smem + RS(dstb + g * 8192, trow, colh * 2)) = f2bf(res);
                            }
                } else {
                    #pragma unroll
                    for (int g = 0; g < 2; ++g)
                        #pragma unroll
                        for (int mt = 0; mt < 2; ++mt)
                            #pragma unroll
                            for (int r = 0; r < 4; ++r) {
                                int trow = mt * 16 + quad * 4 + r;
                                *(unsigned short*)(smem + RS(dstb + g * 8192, trow, (t16 * 16 + lid) * 2)) = f2bf(acc[g][mt][r]);
                            }
                }
            } else {                           // v -> V^T [64 d][32 t]
                #pragma unroll
                for (int g = 0; g < 2; ++g)
                    #pragma unroll
                    for (int mt = 0; mt < 2; ++mt) {
                        int d  = t16 * 16 + lid;
                        int t0 = mt * 16 + quad * 4;
                        s16x4 pk;
                        pk[0] = (short)f2bf(acc[g][mt][0]); pk[1] = (short)f2bf(acc[g][mt][1]);
                        pk[2] = (short)f2bf(acc[g][mt][2]); pk[3] = (short)f2bf(acc[g][mt][3]);
                        *(s16x4*)(smem + VS(V_OFF + (g * 2 + hh) * 4096, d, t0 * 2)) = pk;
                    }
            }
        }
        __syncthreads();

        // ===== attention: r13 verbatim (swapped PV + packed store) ==============
        {
            int g  = wv >> 2;
            int hh = (wv >> 1) & 1;
            int dt = wv & 1;
            int qr  = Q_OFF  + (g * 2 + hh) * 4096;
            int kr  = K_OFF  + (g * 2 + hh) * 4096;
            int vr  = V_OFF  + (g * 2 + hh) * 4096;
            int pvr = PV_OFF + (g * 2 + hh) * 4096;
            int tq = lane & 31;
            int hf = lane >> 5;

            f32x16 sc = fz16();
            #pragma unroll
            for (int j = 0; j < 4; ++j) {
                bf16x8 aK = *(const bf16x8*)(smem + RS(kr, tq, j * 32 + hf * 16));
                bf16x8 bQ = *(const bf16x8*)(smem + RS(qr, tq, j * 32 + hf * 16));
                sc = MFMA32(aK, bQ, sc);
            }
            float pe[16];
            float mx = -1e30f;
            #pragma unroll
            for (int r = 0; r < 16; ++r) {
                int tk = (r & 3) + 8 * (r >> 2) + 4 * hf;
                float v = (tk <= tq) ? sc[r] * 0.125f : -1e30f;
                pe[r] = v;
                mx = fmaxf(mx, v);
            }
            mx = fmaxf(mx, __shfl_xor(mx, 32, 64));
            float sum = 0.f;
            #pragma unroll
            for (int r = 0; r < 16; ++r) {
                float e = __expf(pe[r] - mx);
                pe[r] = e;
                sum += e;
            }
            sum += __shfl_xor(sum, 32, 64);
            float inv = 1.f / sum;
            bf16x8 pa0, pa1;
            #pragma unroll
            for (int i2 = 0; i2 < 8; ++i2) {
                pa0[i2] = (short)f2bf(pe[i2] * inv);
                pa1[i2] = (short)f2bf(pe[8 + i2] * inv);
            }
            // PV, swapped operands (verified r13): lane owns row tq, 4-consec-d runs
            int d = dt * 32 + tq;
            f32x16 o = fz16();
            {
                s16x4 lo = *(const s16x4*)(smem + VS(vr, d, 8 * hf));
                s16x4 hi = *(const s16x4*)(smem + VS(vr, d, 16 + 8 * hf));
                bf16x8 bv;
                bv[0] = lo[0]; bv[1] = lo[1]; bv[2] = lo[2]; bv[3] = lo[3];
                bv[4] = hi[0]; bv[5] = hi[1]; bv[6] = hi[2]; bv[7] = hi[3];
                o = MFMA32(bv, pa0, o);
            }
            {
                s16x4 lo = *(const s16x4*)(smem + VS(vr, d, 32 + 8 * hf));
                s16x4 hi = *(const s16x4*)(smem + VS(vr, d, 48 + 8 * hf));
                bf16x8 bv;
                bv[0] = lo[0]; bv[1] = lo[1]; bv[2] = lo[2]; bv[3] = lo[3];
                bv[4] = hi[0]; bv[5] = hi[1]; bv[6] = hi[2]; bv[7] = hi[3];
                o = MFMA32(bv, pa1, o);
            }
            #pragma unroll
            for (int c = 0; c < 4; ++c) {
                u32x2 pk2;
                pk2[0] = pk_bf(o[4 * c + 0], o[4 * c + 1]);
                pk2[1] = pk_bf(o[4 * c + 2], o[4 * c + 3]);
                int db = dt * 32 + c * 8 + 4 * hf;
                *(u32x2*)(smem + RS(pvr, tq, db * 2)) = pk2;
            }
        }
        __syncthreads();

        // ===== out-projection accumulate — r13 verbatim =========================
        {
            #pragma unroll
            for (int k05h = 0; k05h < 4; ++k05h) {
                int hh   = k05h >> 1;
                int dblk = k05h & 1;
                int kb   = (hpair + hh) * 2 + dblk;
                bf16x8 a[2][2];
                #pragma unroll
                for (int g = 0; g < 2; ++g)
                    #pragma unroll
                    for (int mt = 0; mt < 2; ++mt)
                        a[g][mt] = *(const bf16x8*)(smem + RS(PV_OFF + (g * 2 + hh) * 4096, lid + 16 * mt, dblk * 64 + quad * 16));
                #pragma unroll
                for (int j = 0; j < 4; ++j) {
                    int ct = wv + 8 * j;
                    bf16x8 bw = *(const bf16x8*)(wof + ((long)(ct * 16 + kb)) * 512 + lane * 8);
                    #pragma unroll
                    for (int g = 0; g < 2; ++g)
                        #pragma unroll
                        for (int mt = 0; mt < 2; ++mt)
                            oacc[j][g][mt] = MFMA16(a[g][mt], bw, oacc[j][g][mt]);
                }
            }
        }
        // no barrier: next-iter qkv writes Q/K/V (readers synced at attn barrier);
        // next-iter attn writes PV only after next qkv barrier.
    }

    // ===== write out (+bias) — r13 verbatim =====
    #pragma unroll
    for (int j = 0; j < 4; ++j) {
        int col = (wv + 8 * j) * 16 + lid;
        float bias = b_out[col];
        #pragma unroll
        for (int g = 0; g < 2; ++g) {
            long long bg = g ? base1 : base0;
            #pragma unroll
            for (int mt = 0; mt < 2; ++mt)
                #pragma unroll
                for (int r = 0; r < 4; ++r) {
                    int t = mt * 16 + quad * 4 + r;
                    out[bg + (long long)t * TSTRIDE + col] = oacc[j][g][mt][r] + bias;
                }
        }
    }
}

extern "C" void kernel_launch(void* const* d_in, const int* in_sizes, int n_in,
                              void* d_out, int out_size, void* d_ws, size_t ws_size,
                              hipStream_t stream) {
    const float* x     = (const float*)d_in[0];
    const float* w_qkv = (const float*)d_in[1];
    const float* w_out = (const float*)d_in[2];
    const float* b_out = (const float*)d_in[3];
    float* out = (float*)d_out;
    (void)in_sizes; (void)n_in; (void)out_size; (void)ws_size;

    unsigned short* ws = (unsigned short*)d_ws;   // ~2.1 MB

    taa_prep<<<dim3(4098), dim3(256), 0, stream>>>(w_qkv, w_out, ws);
    taa_main<<<dim3(1024), dim3(512), LDS_SZ, stream>>>(x, ws, b_out, out);
}